// Round 13
// baseline (210.900 us; speedup 1.0000x reference)
//
#include <hip/hip_runtime.h>
#include <hip/hip_bf16.h>

#define WIN 7
#define SHIFT_SZ 3
#define WSQ 49
#define CH 128
#define HW 56
#define LOG2E 1.4426950408889634f
#define QSCALE (0.17677669529663687f * LOG2E)

typedef short s16x8 __attribute__((ext_vector_type(8)));
typedef short s16x4 __attribute__((ext_vector_type(4)));
typedef float f32x4 __attribute__((ext_vector_type(4)));

static __device__ __forceinline__ f32x4 mfma16(s16x4 a, s16x4 b, f32x4 c) {
#if __has_builtin(__builtin_amdgcn_mfma_f32_16x16x16bf16_1k)
  return __builtin_amdgcn_mfma_f32_16x16x16bf16_1k(a, b, c, 0, 0, 0);
#else
  f32x4 d;
  asm("v_mfma_f32_16x16x16_bf16 %0, %1, %2, %3" : "=v"(d) : "v"(a), "v"(b), "v"(c));
  return d;
#endif
}

// ---------------- prep kernels ----------------
// W_Q rows and Q-bias pre-scaled by QSCALE (softmax scale * log2e folded).

__global__ void prep_weights(const float* __restrict__ qkv_kernel,
                             const float* __restrict__ proj_kernel,
                             const float* __restrict__ qkv_bias,
                             __hip_bfloat16* __restrict__ ws) {
  int idx = blockIdx.x * 256 + threadIdx.x;
  if (idx < 49152) {                      // WqkvT [384][128]
    int n = idx >> 7, c = idx & 127;
    float w = qkv_kernel[c * 384 + n];
    if (n < 128) w *= QSCALE;
    ws[idx] = __float2bfloat16(w);
  }
  if (idx < 16384) {                      // WprojT [128][128]
    int n = idx >> 7, c = idx & 127;
    ws[49152 + idx] = __float2bfloat16(proj_kernel[c * 128 + n]);
  }
  if (idx < 384) {                        // scaled bias (f32), after tbl
    float* bf = (float*)(ws + 131072);
    bf[idx] = qkv_bias[idx] * (idx < 128 ? QSCALE : 1.0f);
  }
}

// Only 4 distinct shift masks exist: cls = (wy==7)*2 + (wx==7).
// tbl[cls][h][s][t] = LOG2E * (rel_pos_bias(s,t) + mask(cls,s,t));
// cols t>=49 -> -43280 (kills padded keys), rows s>=49 (dead queries) -> 0
__global__ void prep_tbl(const float* __restrict__ rel_pos_table,
                         __hip_bfloat16* __restrict__ tbl) {
  int idx = blockIdx.x * 256 + threadIdx.x;   // 65536 total
  int t = idx & 63;
  int s = (idx >> 6) & 63;
  int h = (idx >> 12) & 3;
  int cls = idx >> 14;                        // 0..3
  float v;
  if (t >= WSQ) v = -43280.f;
  else if (s >= WSQ) v = 0.f;
  else {
    int i1 = s / 7, j1 = s % 7, i2 = t / 7, j2 = t % 7;
    int ridx = (i1 - i2 + 6) * 13 + (j1 - j2 + 6);
    float bias = rel_pos_table[ridx * 4 + h];
    int wyIs7 = cls >> 1, wxIs7 = cls & 1;
    int rh1 = wyIs7 ? (i1 < 4 ? 1 : 2) : 0;
    int rh2 = wyIs7 ? (i2 < 4 ? 1 : 2) : 0;
    int rw1 = wxIs7 ? (j1 < 4 ? 1 : 2) : 0;
    int rw2 = wxIs7 ? (j2 < 4 ? 1 : 2) : 0;
    float mask = (rh1 == rh2 && rw1 == rw2) ? 0.f : -100.f;
    v = (bias + mask) * LOG2E;
  }
  tbl[idx] = __float2bfloat16(v);
}

// ---------------- fused main kernel ----------------
// one block = one window (4096 blocks), 256 threads = 4 waves = 4 heads.
// Per-wave-private attention: each wave computes its head's FULL K and V
// into registers (kf16/vf16, 16 VGPR each), then per-16-row m-tile:
// Q (8 mfma32, 4-reg transient) -> QK^T (mfma16, acc-init from bias tbl)
// -> in-reg softmax -> P in regs -> PV (mfma16) -> o_lds. K/Q/P/V never
// touch LDS. #pragma unroll 1 on the m-loop keeps transients per-iteration.
// LDS 32768 B: a [64][128] swz @0 | o [64][128] swz @16384. NO overlays.
// Barriers: b1 (x staged) | b2 (o visible). 2 total (R8 had 6).
// (256,5): 5 blocks/CU = 20 waves, reg budget ~102 (est. peak ~84).

__launch_bounds__(256, 5)
__global__ void swin_attn(const float* __restrict__ x,
                          const float* __restrict__ biasf,
                          const float* __restrict__ proj_bias,
                          const __hip_bfloat16* __restrict__ wqkvT,
                          const __hip_bfloat16* __restrict__ wprojT,
                          const __hip_bfloat16* __restrict__ tbl,
                          float* __restrict__ out) {
  __shared__ __align__(16) char smem[32768];
  __hip_bfloat16* a_lds = (__hip_bfloat16*)smem;             // [64][128] swz
  __hip_bfloat16* o_lds = (__hip_bfloat16*)(smem + 16384);   // [64][128] swz

  const int tid = threadIdx.x;
  const int lane = tid & 63;
  const int wv = tid >> 6;          // wave 0..3 == head
  const int g = lane >> 4;          // quarter-wave group
  const int c = lane & 15;
  const int e = c & 7;              // 8-short block XOR mask (rows ≡ c mod 8)

  const int widx = blockIdx.x;
  const int b  = widx >> 6;
  const int wy = (widx >> 3) & 7;
  const int wx = widx & 7;
  const int mc = ((wy == 7) ? 2 : 0) + ((wx == 7) ? 1 : 0);

  // ---- phase 1: stage shifted x-window as bf16 (rows 49..63 zero) ----
  for (int it = tid; it < 1024; it += 256) {
    int s = it >> 4;
    int l16 = it & 15;
    union { s16x8 v; __hip_bfloat16 h[8]; } u;
    if (s < WSQ) {
      int i = s / 7, j = s - i * 7;
      int hh = wy * 7 + i + SHIFT_SZ; if (hh >= HW) hh -= HW;
      int ww = wx * 7 + j + SHIFT_SZ; if (ww >= HW) ww -= HW;
      const float4* src = (const float4*)(x + (((b * HW + hh) * HW + ww) * CH + l16 * 8));
      float4 f0 = src[0], f1 = src[1];
      u.h[0] = __float2bfloat16(f0.x); u.h[1] = __float2bfloat16(f0.y);
      u.h[2] = __float2bfloat16(f0.z); u.h[3] = __float2bfloat16(f0.w);
      u.h[4] = __float2bfloat16(f1.x); u.h[5] = __float2bfloat16(f1.y);
      u.h[6] = __float2bfloat16(f1.z); u.h[7] = __float2bfloat16(f1.w);
    } else {
      #pragma unroll
      for (int q = 0; q < 8; ++q) u.h[q] = __float2bfloat16(0.f);
    }
    *(s16x8*)(a_lds + s * 128 + ((l16 ^ (s & 7)) * 8)) = u.v;
  }
  __syncthreads();   // b1

  // ---- K-pass: head wv's full K (64 tok x 32 d), n-major -> kf16 regs ----
  // kf16[kb][mt]: lane c = token 16mt+c, regs = d = 16kb+4g+r
  s16x4 kf16[2][4];
  {
    f32x4 acc[2][4];
    #pragma unroll
    for (int kb = 0; kb < 2; ++kb) {
      float4 kb4 = *(const float4*)(biasf + 128 + 32 * wv + 16 * kb + 4 * g);
      #pragma unroll
      for (int mt = 0; mt < 4; ++mt) acc[kb][mt] = (f32x4){kb4.x, kb4.y, kb4.z, kb4.w};
    }
    #pragma unroll
    for (int kt = 0; kt < 4; ++kt) {
      s16x8 af[4];
      #pragma unroll
      for (int mt = 0; mt < 4; ++mt)
        af[mt] = *(const s16x8*)(a_lds + (16 * mt + c) * 128 + ((4 * kt + g) ^ e) * 8);
      #pragma unroll
      for (int kb = 0; kb < 2; ++kb) {
        s16x8 bf = *(const s16x8*)(wqkvT + (128 + 32 * wv + 16 * kb + c) * 128 + kt * 32 + g * 8);
        #pragma unroll
        for (int mt = 0; mt < 4; ++mt)
          acc[kb][mt] = __builtin_amdgcn_mfma_f32_16x16x32_bf16(bf, af[mt], acc[kb][mt], 0, 0, 0);
      }
    }
    #pragma unroll
    for (int kb = 0; kb < 2; ++kb)
      #pragma unroll
      for (int mt = 0; mt < 4; ++mt) {
        union { s16x4 v; __hip_bfloat16 h[4]; } u;
        #pragma unroll
        for (int r = 0; r < 4; ++r) u.h[r] = __float2bfloat16(acc[kb][mt][r]);
        kf16[kb][mt] = u.v;
      }
  }

  // ---- V-pass: head wv's full V, m-major -> vf16 regs ----
  // vf16[vt][mt]: lane c = d = 16vt+c, regs = token = 16mt+4g+r
  s16x4 vf16[2][4];
  {
    f32x4 acc[2][4];
    #pragma unroll
    for (int vt = 0; vt < 2; ++vt) {
      float bvb = biasf[256 + 32 * wv + 16 * vt + c];
      #pragma unroll
      for (int mt = 0; mt < 4; ++mt) acc[vt][mt] = (f32x4){bvb, bvb, bvb, bvb};
    }
    #pragma unroll
    for (int kt = 0; kt < 4; ++kt) {
      s16x8 af[4];
      #pragma unroll
      for (int mt = 0; mt < 4; ++mt)
        af[mt] = *(const s16x8*)(a_lds + (16 * mt + c) * 128 + ((4 * kt + g) ^ e) * 8);
      #pragma unroll
      for (int vt = 0; vt < 2; ++vt) {
        s16x8 bv = *(const s16x8*)(wqkvT + (256 + 32 * wv + 16 * vt + c) * 128 + kt * 32 + g * 8);
        #pragma unroll
        for (int mt = 0; mt < 4; ++mt)
          acc[vt][mt] = __builtin_amdgcn_mfma_f32_16x16x32_bf16(af[mt], bv, acc[vt][mt], 0, 0, 0);
      }
    }
    #pragma unroll
    for (int vt = 0; vt < 2; ++vt)
      #pragma unroll
      for (int mt = 0; mt < 4; ++mt) {
        union { s16x4 v; __hip_bfloat16 h[4]; } u;
        #pragma unroll
        for (int r = 0; r < 4; ++r) u.h[r] = __float2bfloat16(acc[vt][mt][r]);
        vf16[vt][mt] = u.v;
      }
  }

  // ---- attention, per 16-row m-tile (transient regs only) ----
  #pragma unroll 1
  for (int m = 0; m < 4; ++m) {
    // Q for rows 16m..16m+15, n-major -> qf[kb] (4 VGPR)
    s16x4 qf[2];
    {
      f32x4 qacc[2];
      #pragma unroll
      for (int kb = 0; kb < 2; ++kb) {
        float4 qb4 = *(const float4*)(biasf + 32 * wv + 16 * kb + 4 * g);
        qacc[kb] = (f32x4){qb4.x, qb4.y, qb4.z, qb4.w};
      }
      #pragma unroll
      for (int kt = 0; kt < 4; ++kt) {
        s16x8 afq = *(const s16x8*)(a_lds + (16 * m + c) * 128 + ((4 * kt + g) ^ e) * 8);
        #pragma unroll
        for (int kb = 0; kb < 2; ++kb) {
          s16x8 bf = *(const s16x8*)(wqkvT + (32 * wv + 16 * kb + c) * 128 + kt * 32 + g * 8);
          qacc[kb] = __builtin_amdgcn_mfma_f32_16x16x32_bf16(bf, afq, qacc[kb], 0, 0, 0);
        }
      }
      #pragma unroll
      for (int kb = 0; kb < 2; ++kb) {
        union { s16x4 v; __hip_bfloat16 h[4]; } u;
        #pragma unroll
        for (int r = 0; r < 4; ++r) u.h[r] = __float2bfloat16(qacc[kb][r]);
        qf[kb] = u.v;
      }
    }
    // QK^T: sc[nt] init from bias tbl (lane c -> s=16m+c; regs -> t=16nt+4g+r)
    const __hip_bfloat16* tb_ =
        tbl + (((mc << 2) + wv) << 12) + (16 * m + c) * 64;
    f32x4 sc[4];
    #pragma unroll
    for (int nt = 0; nt < 4; ++nt) {
      union { s16x4 v; __hip_bfloat16 h[4]; } tv;
      tv.v = *(const s16x4*)(tb_ + 16 * nt + 4 * g);
      #pragma unroll
      for (int r = 0; r < 4; ++r) sc[nt][r] = __bfloat162float(tv.h[r]);
      #pragma unroll
      for (int kb = 0; kb < 2; ++kb)
        sc[nt] = mfma16(kf16[kb][nt], qf[kb], sc[nt]);
    }
    // softmax over t (16 local regs + cross-g shuffles)
    float mx = -1e30f;
    #pragma unroll
    for (int nt = 0; nt < 4; ++nt)
      #pragma unroll
      for (int r = 0; r < 4; ++r) mx = fmaxf(mx, sc[nt][r]);
    mx = fmaxf(mx, __shfl_xor(mx, 16));
    mx = fmaxf(mx, __shfl_xor(mx, 32));
    float sum = 0.f;
    #pragma unroll
    for (int nt = 0; nt < 4; ++nt)
      #pragma unroll
      for (int r = 0; r < 4; ++r) {
        float ex = __builtin_amdgcn_exp2f(sc[nt][r] - mx);
        sc[nt][r] = ex;
        sum += ex;
      }
    s16x4 pf[4];
    #pragma unroll
    for (int nt = 0; nt < 4; ++nt) {
      union { s16x4 v; __hip_bfloat16 h[4]; } u;
      #pragma unroll
      for (int r = 0; r < 4; ++r) u.h[r] = __float2bfloat16(sc[nt][r]);
      pf[nt] = u.v;
    }
    sum += __shfl_xor(sum, 16);
    sum += __shfl_xor(sum, 32);
    float inv = __builtin_amdgcn_rcpf(sum);
    // PV: oacc lane c -> s=16m+c, regs -> d=16vt+4g+r; scale by inv, store
    #pragma unroll
    for (int vt = 0; vt < 2; ++vt) {
      f32x4 oacc = (f32x4){0.f, 0.f, 0.f, 0.f};
      #pragma unroll
      for (int nt = 0; nt < 4; ++nt)
        oacc = mfma16(vf16[vt][nt], pf[nt], oacc);
      union { s16x4 v; __hip_bfloat16 h[4]; } u;
      #pragma unroll
      for (int r = 0; r < 4; ++r) u.h[r] = __float2bfloat16(oacc[r] * inv);
      *(s16x4*)(o_lds + (16 * m + c) * 128 +
                ((4 * wv + 2 * vt + (g >> 1)) ^ e) * 8 + (g & 1) * 4) = u.v;
    }
  }
  __syncthreads();   // b2: o visible

  // ---- proj GEMM: wave owns n-tiles {2wv, 2wv+1} (bias in acc-init) ----
  #pragma unroll
  for (int ntl = 0; ntl < 2; ++ntl) {
    int nt = 2 * wv + ntl;
    float4 pb4 = *(const float4*)(proj_bias + 16 * nt + 4 * g);
    f32x4 pacc[4];
    #pragma unroll
    for (int mt = 0; mt < 4; ++mt) pacc[mt] = (f32x4){pb4.x, pb4.y, pb4.z, pb4.w};
    #pragma unroll
    for (int kt = 0; kt < 4; ++kt) {
      s16x8 bfp = *(const s16x8*)(wprojT + (16 * nt + c) * 128 + kt * 32 + g * 8);
      #pragma unroll
      for (int mt = 0; mt < 4; ++mt) {
        s16x8 afo = *(const s16x8*)(o_lds + (16 * mt + c) * 128 + ((4 * kt + g) ^ e) * 8);
        pacc[mt] = __builtin_amdgcn_mfma_f32_16x16x32_bf16(bfp, afo, pacc[mt], 0, 0, 0);
      }
    }
    #pragma unroll
    for (int mt = 0; mt < 4; ++mt) {
      int s = 16 * mt + c;
      if (s < WSQ) {
        int i = s / 7, j = s - i * 7;
        int hh = wy * 7 + i + SHIFT_SZ; if (hh >= HW) hh -= HW;
        int ww = wx * 7 + j + SHIFT_SZ; if (ww >= HW) ww -= HW;
        float4 v;
        v.x = pacc[mt][0];
        v.y = pacc[mt][1];
        v.z = pacc[mt][2];
        v.w = pacc[mt][3];
        *(float4*)(out + ((b * HW + hh) * HW + ww) * CH + 16 * nt + 4 * g) = v;
      }
    }
  }
}

extern "C" void kernel_launch(void* const* d_in, const int* in_sizes, int n_in,
                              void* d_out, int out_size, void* d_ws, size_t ws_size,
                              hipStream_t stream) {
  const float* x            = (const float*)d_in[0];
  const float* qkv_kernel   = (const float*)d_in[1];
  const float* qkv_bias     = (const float*)d_in[2];
  const float* proj_kernel  = (const float*)d_in[3];
  const float* proj_bias    = (const float*)d_in[4];
  const float* rel_pos_tbl  = (const float*)d_in[5];
  float* out = (float*)d_out;

  __hip_bfloat16* wsb    = (__hip_bfloat16*)d_ws;
  __hip_bfloat16* wqkvT  = wsb;            // 49152 elems
  __hip_bfloat16* wprojT = wsb + 49152;    // 16384 elems
  __hip_bfloat16* tbl    = wsb + 65536;    // 65536 elems (4 mask classes)
  const float* biasf     = (const float*)(wsb + 131072);  // 384 f32 (scaled)

  prep_weights<<<dim3(192), dim3(256), 0, stream>>>(qkv_kernel, proj_kernel,
                                                    qkv_bias, wsb);
  prep_tbl<<<dim3(256), dim3(256), 0, stream>>>(rel_pos_tbl, tbl);
  swin_attn<<<dim3(4096), dim3(256), 0, stream>>>(x, biasf, proj_bias,
                                                  wqkvT, wprojT, tbl, out);
}

// Round 14
// 194.043 us; speedup vs baseline: 1.0869x; 1.0869x over previous
//
#include <hip/hip_runtime.h>
#include <hip/hip_bf16.h>

#define WIN 7
#define SHIFT_SZ 3
#define WSQ 49
#define CH 128
#define HW 56
#define LOG2E 1.4426950408889634f
#define QSCALE (0.17677669529663687f * LOG2E)

typedef short s16x8 __attribute__((ext_vector_type(8)));
typedef short s16x4 __attribute__((ext_vector_type(4)));
typedef float f32x4 __attribute__((ext_vector_type(4)));

static __device__ __forceinline__ f32x4 mfma16(s16x4 a, s16x4 b, f32x4 c) {
#if __has_builtin(__builtin_amdgcn_mfma_f32_16x16x16bf16_1k)
  return __builtin_amdgcn_mfma_f32_16x16x16bf16_1k(a, b, c, 0, 0, 0);
#else
  f32x4 d;
  asm("v_mfma_f32_16x16x16_bf16 %0, %1, %2, %3" : "=v"(d) : "v"(a), "v"(b), "v"(c));
  return d;
#endif
}

// ---------------- prep kernels (R8 verbatim) ----------------

__global__ void prep_weights(const float* __restrict__ qkv_kernel,
                             const float* __restrict__ proj_kernel,
                             __hip_bfloat16* __restrict__ ws) {
  int idx = blockIdx.x * 256 + threadIdx.x;
  if (idx < 49152) {                      // WqkvT [384][128]
    int n = idx >> 7, c = idx & 127;
    ws[idx] = __float2bfloat16(qkv_kernel[c * 384 + n]);
  }
  if (idx < 16384) {                      // WprojT [128][128]
    int n = idx >> 7, c = idx & 127;
    ws[49152 + idx] = __float2bfloat16(proj_kernel[c * 128 + n]);
  }
}

__global__ void prep_tbl(const float* __restrict__ rel_pos_table,
                         __hip_bfloat16* __restrict__ tbl) {
  int idx = blockIdx.x * 256 + threadIdx.x;   // 65536 total
  int t = idx & 63;
  int s = (idx >> 6) & 63;
  int h = (idx >> 12) & 3;
  int cls = idx >> 14;                        // 0..3
  float v;
  if (t >= WSQ) v = -43280.f;
  else if (s >= WSQ) v = 0.f;
  else {
    int i1 = s / 7, j1 = s % 7, i2 = t / 7, j2 = t % 7;
    int ridx = (i1 - i2 + 6) * 13 + (j1 - j2 + 6);
    float bias = rel_pos_table[ridx * 4 + h];
    int wyIs7 = cls >> 1, wxIs7 = cls & 1;
    int rh1 = wyIs7 ? (i1 < 4 ? 1 : 2) : 0;
    int rh2 = wyIs7 ? (i2 < 4 ? 1 : 2) : 0;
    int rw1 = wxIs7 ? (j1 < 4 ? 1 : 2) : 0;
    int rw2 = wxIs7 ? (j2 < 4 ? 1 : 2) : 0;
    float mask = (rh1 == rh2 && rw1 == rw2) ? 0.f : -100.f;
    v = (bias + mask) * LOG2E;
  }
  tbl[idx] = __float2bfloat16(v);
}

// ============ SPLIT PATH ============
// Kernel A: QKV GEMM per window; fragments stored to GLOBAL in the exact
// s16x4 layout kernel B consumes. Per (win,head): Q/K at
// base + kb*1024 + tok*16 + g*4 (tok-major, d-quads); V at
// base + vt*1024 + d*64 + mt*16 + g*4 (d-major, tok-quads).
// LDS 16KB (a only), 1 barrier. MFMA passes = R8 verbatim.

__launch_bounds__(512, 6)
__global__ void qkv_win(const float* __restrict__ x,
                        const float* __restrict__ qkv_bias,
                        const __hip_bfloat16* __restrict__ wqkvT,
                        __hip_bfloat16* __restrict__ qg,
                        __hip_bfloat16* __restrict__ kg,
                        __hip_bfloat16* __restrict__ vg) {
  __shared__ __align__(16) char smem[16384];
  __hip_bfloat16* a_lds = (__hip_bfloat16*)smem;   // [64][128] swz

  const int tid = threadIdx.x;
  const int lane = tid & 63;
  const int wv = tid >> 6;
  const int g = lane >> 4;
  const int c = lane & 15;
  const int e = c & 7;

  const int widx = blockIdx.x;
  const int b  = widx >> 6;
  const int wy = (widx >> 3) & 7;
  const int wx = widx & 7;

  // ---- stage shifted x-window (R8 verbatim) ----
  for (int it = tid; it < 1024; it += 512) {
    int s = it >> 4;
    int l16 = it & 15;
    union { s16x8 v; __hip_bfloat16 h[8]; } u;
    if (s < WSQ) {
      int i = s / 7, j = s - i * 7;
      int hh = wy * 7 + i + SHIFT_SZ; if (hh >= HW) hh -= HW;
      int ww = wx * 7 + j + SHIFT_SZ; if (ww >= HW) ww -= HW;
      const float4* src = (const float4*)(x + (((b * HW + hh) * HW + ww) * CH + l16 * 8));
      float4 f0 = src[0], f1 = src[1];
      u.h[0] = __float2bfloat16(f0.x); u.h[1] = __float2bfloat16(f0.y);
      u.h[2] = __float2bfloat16(f0.z); u.h[3] = __float2bfloat16(f0.w);
      u.h[4] = __float2bfloat16(f1.x); u.h[5] = __float2bfloat16(f1.y);
      u.h[6] = __float2bfloat16(f1.z); u.h[7] = __float2bfloat16(f1.w);
    } else {
      #pragma unroll
      for (int q = 0; q < 8; ++q) u.h[q] = __float2bfloat16(0.f);
    }
    *(s16x8*)(a_lds + s * 128 + ((l16 ^ (s & 7)) * 8)) = u.v;
  }
  __syncthreads();

  // ---- pass A: V tile (n-tile 16+wv), m-major (R8 verbatim MFMAs) ----
  {
    f32x4 acc_v[4];
    #pragma unroll
    for (int mt = 0; mt < 4; ++mt) acc_v[mt] = (f32x4){0.f, 0.f, 0.f, 0.f};
    #pragma unroll
    for (int kt = 0; kt < 4; ++kt) {
      s16x8 bv = *(const s16x8*)(wqkvT + (16 * (16 + wv) + c) * 128 + kt * 32 + g * 8);
      #pragma unroll
      for (int mt = 0; mt < 4; ++mt) {
        s16x8 af = *(const s16x8*)(a_lds + (16 * mt + c) * 128 + ((4 * kt + g) ^ e) * 8);
        acc_v[mt] = __builtin_amdgcn_mfma_f32_16x16x32_bf16(af, bv, acc_v[mt], 0, 0, 0);
      }
    }
    int hv = wv >> 1;
    int vt = wv & 1;
    float bvb = qkv_bias[256 + wv * 16 + c];
    __hip_bfloat16* vdst = vg + (((widx * 4 + hv) * 2 + vt) * 16 + c) * 64;
    #pragma unroll
    for (int mt = 0; mt < 4; ++mt) {
      union { s16x4 v; __hip_bfloat16 h[4]; } u;
      #pragma unroll
      for (int r = 0; r < 4; ++r) u.h[r] = __float2bfloat16(acc_v[mt][r] + bvb);
      *(s16x4*)(vdst + mt * 16 + g * 4) = u.v;
    }
  }

  // ---- pass B: Q/K tiles {2wv, 2wv+1}, n-major (R8 verbatim MFMAs) ----
  {
    f32x4 acc[2][4];
    #pragma unroll
    for (int ntl = 0; ntl < 2; ++ntl)
      #pragma unroll
      for (int mt = 0; mt < 4; ++mt) acc[ntl][mt] = (f32x4){0.f, 0.f, 0.f, 0.f};
    #pragma unroll
    for (int kt = 0; kt < 4; ++kt) {
      s16x8 af[4];
      #pragma unroll
      for (int mt = 0; mt < 4; ++mt)
        af[mt] = *(const s16x8*)(a_lds + (16 * mt + c) * 128 + ((4 * kt + g) ^ e) * 8);
      #pragma unroll
      for (int ntl = 0; ntl < 2; ++ntl) {
        s16x8 bf = *(const s16x8*)(wqkvT + (16 * (2 * wv + ntl) + c) * 128 + kt * 32 + g * 8);
        #pragma unroll
        for (int mt = 0; mt < 4; ++mt)
          acc[ntl][mt] = __builtin_amdgcn_mfma_f32_16x16x32_bf16(bf, af[mt], acc[ntl][mt], 0, 0, 0);
      }
    }
    const float scale = (wv < 4) ? QSCALE : 1.0f;
    #pragma unroll
    for (int ntl = 0; ntl < 2; ++ntl) {
      int qt = 2 * wv + ntl;
      int head = (qt >> 1) & 3;
      int kb = qt & 1;
      float4 b4 = *(const float4*)(qkv_bias + qt * 16 + 4 * g);
      __hip_bfloat16* dst = (qt < 8 ? qg : kg) + ((widx * 4 + head) * 2 + kb) * 1024;
      #pragma unroll
      for (int mt = 0; mt < 4; ++mt) {
        union { s16x4 v; __hip_bfloat16 h[4]; } u;
        u.h[0] = __float2bfloat16((acc[ntl][mt][0] + b4.x) * scale);
        u.h[1] = __float2bfloat16((acc[ntl][mt][1] + b4.y) * scale);
        u.h[2] = __float2bfloat16((acc[ntl][mt][2] + b4.z) * scale);
        u.h[3] = __float2bfloat16((acc[ntl][mt][3] + b4.w) * scale);
        *(s16x4*)(dst + (16 * mt + c) * 16 + g * 4) = u.v;
      }
    }
  }
}

// Kernel B: attention + proj. 256 threads = 4 waves = 4 heads.
// kf16/vf16 LOADED from global (no producer accs co-live -> no spill trap).
// LDS 16KB (o only), ONE barrier. 5 blocks/CU = 20 waves.

__launch_bounds__(256, 5)
__global__ void attn_win(const float* __restrict__ proj_bias,
                         const __hip_bfloat16* __restrict__ wprojT,
                         const __hip_bfloat16* __restrict__ tbl,
                         const __hip_bfloat16* __restrict__ qg,
                         const __hip_bfloat16* __restrict__ kg,
                         const __hip_bfloat16* __restrict__ vg,
                         float* __restrict__ out) {
  __shared__ __align__(16) char smem[16384];
  __hip_bfloat16* o_lds = (__hip_bfloat16*)smem;   // [64][128] swz

  const int tid = threadIdx.x;
  const int lane = tid & 63;
  const int wv = tid >> 6;          // wave 0..3 == head
  const int g = lane >> 4;
  const int c = lane & 15;
  const int e = c & 7;

  const int widx = blockIdx.x;
  const int b  = widx >> 6;
  const int wy = (widx >> 3) & 7;
  const int wx = widx & 7;
  const int mc = ((wy == 7) ? 2 : 0) + ((wx == 7) ? 1 : 0);

  // ---- load this head's K and V fragments (coalesced, L2/L3) ----
  s16x4 kf16[2][4];   // [kb][nt]: lane c = token 16nt+c, regs = d
  const __hip_bfloat16* kbase = kg + (widx * 4 + wv) * 2048;
  #pragma unroll
  for (int kb = 0; kb < 2; ++kb)
    #pragma unroll
    for (int nt = 0; nt < 4; ++nt)
      kf16[kb][nt] = *(const s16x4*)(kbase + kb * 1024 + (16 * nt + c) * 16 + g * 4);
  s16x4 vf16[2][4];   // [vt][mt]: lane c = d 16vt+c, regs = token 16mt+4g+r
  const __hip_bfloat16* vbase = vg + (widx * 4 + wv) * 2048;
  #pragma unroll
  for (int vt = 0; vt < 2; ++vt)
    #pragma unroll
    for (int mt = 0; mt < 4; ++mt)
      vf16[vt][mt] = *(const s16x4*)(vbase + vt * 1024 + c * 64 + mt * 16 + g * 4);

  const __hip_bfloat16* qbase = qg + (widx * 4 + wv) * 2048;

  // ---- attention per 16-row m-tile ----
  #pragma unroll 1
  for (int m = 0; m < 4; ++m) {
    s16x4 qf[2];
    #pragma unroll
    for (int kb = 0; kb < 2; ++kb)
      qf[kb] = *(const s16x4*)(qbase + kb * 1024 + (16 * m + c) * 16 + g * 4);
    // issue tbl loads early; consume after MFMAs (R11 lesson: keep global
    // latency off the MFMA critical path)
    const __hip_bfloat16* tb_ =
        tbl + (((mc << 2) + wv) << 12) + (16 * m + c) * 64;
    union { s16x4 v; __hip_bfloat16 h[4]; } tv[4];
    #pragma unroll
    for (int nt = 0; nt < 4; ++nt) tv[nt].v = *(const s16x4*)(tb_ + 16 * nt + 4 * g);
    f32x4 sc[4];
    #pragma unroll
    for (int nt = 0; nt < 4; ++nt) {
      sc[nt] = (f32x4){0.f, 0.f, 0.f, 0.f};
      #pragma unroll
      for (int kb = 0; kb < 2; ++kb)
        sc[nt] = mfma16(kf16[kb][nt], qf[kb], sc[nt]);
    }
    #pragma unroll
    for (int nt = 0; nt < 4; ++nt)
      #pragma unroll
      for (int r = 0; r < 4; ++r) sc[nt][r] += __bfloat162float(tv[nt].h[r]);
    float mx = -1e30f;
    #pragma unroll
    for (int nt = 0; nt < 4; ++nt)
      #pragma unroll
      for (int r = 0; r < 4; ++r) mx = fmaxf(mx, sc[nt][r]);
    mx = fmaxf(mx, __shfl_xor(mx, 16));
    mx = fmaxf(mx, __shfl_xor(mx, 32));
    float sum = 0.f;
    #pragma unroll
    for (int nt = 0; nt < 4; ++nt)
      #pragma unroll
      for (int r = 0; r < 4; ++r) {
        float ex = __builtin_amdgcn_exp2f(sc[nt][r] - mx);
        sc[nt][r] = ex;
        sum += ex;
      }
    s16x4 pf[4];   // unnormalized P (deferred normalization)
    #pragma unroll
    for (int nt = 0; nt < 4; ++nt) {
      union { s16x4 v; __hip_bfloat16 h[4]; } u;
      #pragma unroll
      for (int r = 0; r < 4; ++r) u.h[r] = __float2bfloat16(sc[nt][r]);
      pf[nt] = u.v;
    }
    sum += __shfl_xor(sum, 16);
    sum += __shfl_xor(sum, 32);
    float inv = __builtin_amdgcn_rcpf(sum);
    #pragma unroll
    for (int vt = 0; vt < 2; ++vt) {
      f32x4 oacc = (f32x4){0.f, 0.f, 0.f, 0.f};
      #pragma unroll
      for (int nt = 0; nt < 4; ++nt)
        oacc = mfma16(vf16[vt][nt], pf[nt], oacc);
      union { s16x4 v; __hip_bfloat16 h[4]; } u;
      #pragma unroll
      for (int r = 0; r < 4; ++r) u.h[r] = __float2bfloat16(oacc[r] * inv);
      *(s16x4*)(o_lds + (16 * m + c) * 128 +
                ((4 * wv + 2 * vt + (g >> 1)) ^ e) * 8 + (g & 1) * 4) = u.v;
    }
  }
  __syncthreads();   // o visible (the ONLY barrier)

  // ---- proj GEMM: wave owns n-tiles {2wv, 2wv+1} ----
  #pragma unroll
  for (int ntl = 0; ntl < 2; ++ntl) {
    int nt = 2 * wv + ntl;
    float4 pb4 = *(const float4*)(proj_bias + 16 * nt + 4 * g);
    f32x4 pacc[4];
    #pragma unroll
    for (int mt = 0; mt < 4; ++mt) pacc[mt] = (f32x4){pb4.x, pb4.y, pb4.z, pb4.w};
    #pragma unroll
    for (int kt = 0; kt < 4; ++kt) {
      s16x8 bfp = *(const s16x8*)(wprojT + (16 * nt + c) * 128 + kt * 32 + g * 8);
      #pragma unroll
      for (int mt = 0; mt < 4; ++mt) {
        s16x8 afo = *(const s16x8*)(o_lds + (16 * mt + c) * 128 + ((4 * kt + g) ^ e) * 8);
        pacc[mt] = __builtin_amdgcn_mfma_f32_16x16x32_bf16(bfp, afo, pacc[mt], 0, 0, 0);
      }
    }
    #pragma unroll
    for (int mt = 0; mt < 4; ++mt) {
      int s = 16 * mt + c;
      if (s < WSQ) {
        int i = s / 7, j = s - i * 7;
        int hh = wy * 7 + i + SHIFT_SZ; if (hh >= HW) hh -= HW;
        int ww = wx * 7 + j + SHIFT_SZ; if (ww >= HW) ww -= HW;
        float4 v;
        v.x = pacc[mt][0];
        v.y = pacc[mt][1];
        v.z = pacc[mt][2];
        v.w = pacc[mt][3];
        *(float4*)(out + ((b * HW + hh) * HW + ww) * CH + 16 * nt + 4 * g) = v;
      }
    }
  }
}

// ============ FALLBACK: R8 fused kernel, verbatim (126.8 us) ============

__launch_bounds__(512, 6)
__global__ void swin_attn_fused(const float* __restrict__ x,
                                const float* __restrict__ qkv_bias,
                                const float* __restrict__ proj_bias,
                                const __hip_bfloat16* __restrict__ wqkvT,
                                const __hip_bfloat16* __restrict__ wprojT,
                                const __hip_bfloat16* __restrict__ tbl,
                                float* __restrict__ out) {
  __shared__ __align__(16) char smem[53248];
  __hip_bfloat16* a_lds  = (__hip_bfloat16*)smem;
  __hip_bfloat16* q_lds  = (__hip_bfloat16*)smem;
  __hip_bfloat16* k_lds  = (__hip_bfloat16*)(smem + 18432);
  __hip_bfloat16* vt_lds = (__hip_bfloat16*)(smem + 36864);
  __hip_bfloat16* p_lds  = (__hip_bfloat16*)smem;
  __hip_bfloat16* o_lds  = (__hip_bfloat16*)(smem + 36864);

  const int tid = threadIdx.x;
  const int lane = tid & 63;
  const int wv = tid >> 6;
  const int g = lane >> 4;
  const int c = lane & 15;
  const int e = c & 7;

  const int widx = blockIdx.x;
  const int b  = widx >> 6;
  const int wy = (widx >> 3) & 7;
  const int wx = widx & 7;
  const int mc = ((wy == 7) ? 2 : 0) + ((wx == 7) ? 1 : 0);

  for (int it = tid; it < 1024; it += 512) {
    int s = it >> 4;
    int l16 = it & 15;
    union { s16x8 v; __hip_bfloat16 h[8]; } u;
    if (s < WSQ) {
      int i = s / 7, j = s - i * 7;
      int hh = wy * 7 + i + SHIFT_SZ; if (hh >= HW) hh -= HW;
      int ww = wx * 7 + j + SHIFT_SZ; if (ww >= HW) ww -= HW;
      const float4* src = (const float4*)(x + (((b * HW + hh) * HW + ww) * CH + l16 * 8));
      float4 f0 = src[0], f1 = src[1];
      u.h[0] = __float2bfloat16(f0.x); u.h[1] = __float2bfloat16(f0.y);
      u.h[2] = __float2bfloat16(f0.z); u.h[3] = __float2bfloat16(f0.w);
      u.h[4] = __float2bfloat16(f1.x); u.h[5] = __float2bfloat16(f1.y);
      u.h[6] = __float2bfloat16(f1.z); u.h[7] = __float2bfloat16(f1.w);
    } else {
      #pragma unroll
      for (int q = 0; q < 8; ++q) u.h[q] = __float2bfloat16(0.f);
    }
    *(s16x8*)(a_lds + s * 128 + ((l16 ^ (s & 7)) * 8)) = u.v;
  }
  __syncthreads();

  {
    f32x4 acc_v[4];
    #pragma unroll
    for (int mt = 0; mt < 4; ++mt) acc_v[mt] = (f32x4){0.f, 0.f, 0.f, 0.f};
    #pragma unroll
    for (int kt = 0; kt < 4; ++kt) {
      s16x8 bv = *(const s16x8*)(wqkvT + (16 * (16 + wv) + c) * 128 + kt * 32 + g * 8);
      #pragma unroll
      for (int mt = 0; mt < 4; ++mt) {
        s16x8 af = *(const s16x8*)(a_lds + (16 * mt + c) * 128 + ((4 * kt + g) ^ e) * 8);
        acc_v[mt] = __builtin_amdgcn_mfma_f32_16x16x32_bf16(af, bv, acc_v[mt], 0, 0, 0);
      }
    }
    int hv = wv >> 1;
    int d = (wv & 1) * 16 + c;
    float bvb = qkv_bias[256 + wv * 16 + c];
    __hip_bfloat16* vdst = vt_lds + (hv * 32 + d) * 64;
    #pragma unroll
    for (int mt = 0; mt < 4; ++mt) {
      union { s16x4 v; __hip_bfloat16 h[4]; } u;
      #pragma unroll
      for (int r = 0; r < 4; ++r) u.h[r] = __float2bfloat16(acc_v[mt][r] + bvb);
      *(s16x4*)(vdst + ((2 * mt + (g >> 1)) ^ e) * 8 + (g & 1) * 4) = u.v;
    }
  }

  {
    f32x4 acc[2][4];
    #pragma unroll
    for (int ntl = 0; ntl < 2; ++ntl)
      #pragma unroll
      for (int mt = 0; mt < 4; ++mt) acc[ntl][mt] = (f32x4){0.f, 0.f, 0.f, 0.f};
    #pragma unroll
    for (int kt = 0; kt < 4; ++kt) {
      s16x8 af[4];
      #pragma unroll
      for (int mt = 0; mt < 4; ++mt)
        af[mt] = *(const s16x8*)(a_lds + (16 * mt + c) * 128 + ((4 * kt + g) ^ e) * 8);
      #pragma unroll
      for (int ntl = 0; ntl < 2; ++ntl) {
        s16x8 bf = *(const s16x8*)(wqkvT + (16 * (2 * wv + ntl) + c) * 128 + kt * 32 + g * 8);
        #pragma unroll
        for (int mt = 0; mt < 4; ++mt)
          acc[ntl][mt] = __builtin_amdgcn_mfma_f32_16x16x32_bf16(bf, af[mt], acc[ntl][mt], 0, 0, 0);
      }
    }
    const float scale = (wv < 4) ? QSCALE : 1.0f;
    if (wv >= 4) {
      #pragma unroll
      for (int ntl = 0; ntl < 2; ++ntl) {
        int qt = 2 * wv + ntl;
        int h = (qt >> 1) & 3;
        int d0 = (qt & 1) * 16 + 4 * g;
        float4 b4 = *(const float4*)(qkv_bias + qt * 16 + 4 * g);
        __hip_bfloat16* dst = k_lds + h * 2304 + d0;
        #pragma unroll
        for (int mt = 0; mt < 4; ++mt) {
          union { s16x4 v; __hip_bfloat16 h[4]; } u;
          u.h[0] = __float2bfloat16((acc[ntl][mt][0] + b4.x) * scale);
          u.h[1] = __float2bfloat16((acc[ntl][mt][1] + b4.y) * scale);
          u.h[2] = __float2bfloat16((acc[ntl][mt][2] + b4.z) * scale);
          u.h[3] = __float2bfloat16((acc[ntl][mt][3] + b4.w) * scale);
          *(s16x4*)(dst + (16 * mt + c) * 36) = u.v;
        }
      }
    }
    __syncthreads();
    if (wv < 4) {
      #pragma unroll
      for (int ntl = 0; ntl < 2; ++ntl) {
        int qt = 2 * wv + ntl;
        int h = (qt >> 1) & 3;
        int d0 = (qt & 1) * 16 + 4 * g;
        float4 b4 = *(const float4*)(qkv_bias + qt * 16 + 4 * g);
        __hip_bfloat16* dst = q_lds + h * 2304 + d0;
        #pragma unroll
        for (int mt = 0; mt < 4; ++mt) {
          union { s16x4 v; __hip_bfloat16 h[4]; } u;
          u.h[0] = __float2bfloat16((acc[ntl][mt][0] + b4.x) * scale);
          u.h[1] = __float2bfloat16((acc[ntl][mt][1] + b4.y) * scale);
          u.h[2] = __float2bfloat16((acc[ntl][mt][2] + b4.z) * scale);
          u.h[3] = __float2bfloat16((acc[ntl][mt][3] + b4.w) * scale);
          *(s16x4*)(dst + (16 * mt + c) * 36) = u.v;
        }
      }
    }
  }
  __syncthreads();

  const int h3 = wv >> 1;
  const int mh = wv & 1;
  s16x8 qf[2], kf[4];
  #pragma unroll
  for (int m = 0; m < 2; ++m) {
    const __hip_bfloat16* p = q_lds + (h3 * 64 + 16 * (2 * mh + m) + c) * 36 + g * 8;
    *(s16x4*)&qf[m] = *(const s16x4*)p;
    *(((s16x4*)&qf[m]) + 1) = *(const s16x4*)(p + 4);
  }
  #pragma unroll
  for (int nt = 0; nt < 4; ++nt) {
    const __hip_bfloat16* p = k_lds + (h3 * 64 + 16 * nt + c) * 36 + g * 8;
    *(s16x4*)&kf[nt] = *(const s16x4*)p;
    *(((s16x4*)&kf[nt]) + 1) = *(const s16x4*)(p + 4);
  }
  __syncthreads();

  #pragma unroll
  for (int m = 0; m < 2; ++m) {
    f32x4 sc[4];
    #pragma unroll
    for (int nt = 0; nt < 4; ++nt) {
      sc[nt] = (f32x4){0.f, 0.f, 0.f, 0.f};
      sc[nt] = __builtin_amdgcn_mfma_f32_16x16x32_bf16(kf[nt], qf[m], sc[nt], 0, 0, 0);
    }
    const __hip_bfloat16* tb_ =
        tbl + (((mc << 2) + h3) << 12) + (32 * mh + 16 * m + c) * 64;
    #pragma unroll
    for (int nt = 0; nt < 4; ++nt) {
      union { s16x4 v; __hip_bfloat16 h[4]; } tv;
      tv.v = *(const s16x4*)(tb_ + 16 * nt + 4 * g);
      #pragma unroll
      for (int r = 0; r < 4; ++r) sc[nt][r] += __bfloat162float(tv.h[r]);
    }
    float mx = -1e30f;
    #pragma unroll
    for (int nt = 0; nt < 4; ++nt)
      #pragma unroll
      for (int r = 0; r < 4; ++r) mx = fmaxf(mx, sc[nt][r]);
    mx = fmaxf(mx, __shfl_xor(mx, 16));
    mx = fmaxf(mx, __shfl_xor(mx, 32));
    float sum = 0.f;
    #pragma unroll
    for (int nt = 0; nt < 4; ++nt)
      #pragma unroll
      for (int r = 0; r < 4; ++r) {
        float e2 = __builtin_amdgcn_exp2f(sc[nt][r] - mx);
        sc[nt][r] = e2;
        sum += e2;
      }
    sum += __shfl_xor(sum, 16);
    sum += __shfl_xor(sum, 32);
    float inv = __builtin_amdgcn_rcpf(sum);
    __hip_bfloat16* prow = p_lds + (h3 * 64 + 16 * (2 * mh + m) + c) * 64;
    #pragma unroll
    for (int nt = 0; nt < 4; ++nt) {
      union { s16x4 v; __hip_bfloat16 h[4]; } u;
      #pragma unroll
      for (int r = 0; r < 4; ++r) u.h[r] = __float2bfloat16(sc[nt][r] * inv);
      *(s16x4*)(prow + ((2 * nt + (g >> 1)) ^ e) * 8 + (g & 1) * 4) = u.v;
    }
  }

  f32x4 oacc[2][2];
  #pragma unroll
  for (int m = 0; m < 2; ++m)
    #pragma unroll
    for (int ntd = 0; ntd < 2; ++ntd) oacc[m][ntd] = (f32x4){0.f, 0.f, 0.f, 0.f};
  #pragma unroll
  for (int kt = 0; kt < 2; ++kt) {
    s16x8 vfr[2], pfr[2];
    #pragma unroll
    for (int ntd = 0; ntd < 2; ++ntd)
      vfr[ntd] = *(const s16x8*)(vt_lds + (h3 * 32 + 16 * ntd + c) * 64 +
                                 (((4 * kt + g) ^ e) * 8));
    #pragma unroll
    for (int m = 0; m < 2; ++m)
      pfr[m] = *(const s16x8*)(p_lds + (h3 * 64 + 16 * (2 * mh + m) + c) * 64 +
                               (((4 * kt + g) ^ e) * 8));
    #pragma unroll
    for (int m = 0; m < 2; ++m)
      #pragma unroll
      for (int ntd = 0; ntd < 2; ++ntd)
        oacc[m][ntd] = __builtin_amdgcn_mfma_f32_16x16x32_bf16(vfr[ntd], pfr[m], oacc[m][ntd], 0, 0, 0);
  }
  __syncthreads();

  #pragma unroll
  for (int m = 0; m < 2; ++m)
    #pragma unroll
    for (int ntd = 0; ntd < 2; ++ntd) {
      union { s16x4 v; __hip_bfloat16 h[4]; } u;
      #pragma unroll
      for (int r = 0; r < 4; ++r) u.h[r] = __float2bfloat16(oacc[m][ntd][r]);
      *(s16x4*)(o_lds + (32 * mh + 16 * m + c) * 128 +
                ((4 * h3 + 2 * ntd + (g >> 1)) ^ e) * 8 + (g & 1) * 4) = u.v;
    }
  __syncthreads();

  {
    f32x4 pacc[4];
    #pragma unroll
    for (int mt = 0; mt < 4; ++mt) pacc[mt] = (f32x4){0.f, 0.f, 0.f, 0.f};
    #pragma unroll
    for (int kt = 0; kt < 4; ++kt) {
      s16x8 bfp = *(const s16x8*)(wprojT + (16 * wv + c) * 128 + kt * 32 + g * 8);
      #pragma unroll
      for (int mt = 0; mt < 4; ++mt) {
        s16x8 afo = *(const s16x8*)(o_lds + (16 * mt + c) * 128 + ((4 * kt + g) ^ e) * 8);
        pacc[mt] = __builtin_amdgcn_mfma_f32_16x16x32_bf16(bfp, afo, pacc[mt], 0, 0, 0);
      }
    }
    float4 pb4 = *(const float4*)(proj_bias + 16 * wv + 4 * g);
    #pragma unroll
    for (int mt = 0; mt < 4; ++mt) {
      int s = 16 * mt + c;
      if (s < WSQ) {
        int i = s / 7, j = s - i * 7;
        int hh = wy * 7 + i + SHIFT_SZ; if (hh >= HW) hh -= HW;
        int ww = wx * 7 + j + SHIFT_SZ; if (ww >= HW) ww -= HW;
        float4 v;
        v.x = pacc[mt][0] + pb4.x;
        v.y = pacc[mt][1] + pb4.y;
        v.z = pacc[mt][2] + pb4.z;
        v.w = pacc[mt][3] + pb4.w;
        *(float4*)(out + ((b * HW + hh) * HW + ww) * CH + 16 * wv + 4 * g) = v;
      }
    }
  }
}

extern "C" void kernel_launch(void* const* d_in, const int* in_sizes, int n_in,
                              void* d_out, int out_size, void* d_ws, size_t ws_size,
                              hipStream_t stream) {
  const float* x            = (const float*)d_in[0];
  const float* qkv_kernel   = (const float*)d_in[1];
  const float* qkv_bias     = (const float*)d_in[2];
  const float* proj_kernel  = (const float*)d_in[3];
  const float* proj_bias    = (const float*)d_in[4];
  const float* rel_pos_tbl  = (const float*)d_in[5];
  float* out = (float*)d_out;

  __hip_bfloat16* wsb    = (__hip_bfloat16*)d_ws;
  __hip_bfloat16* wqkvT  = wsb;            // 49152 elems
  __hip_bfloat16* wprojT = wsb + 49152;    // 16384 elems
  __hip_bfloat16* tbl    = wsb + 65536;    // 65536 elems (4 mask classes)

  prep_weights<<<dim3(192), dim3(256), 0, stream>>>(qkv_kernel, proj_kernel, wsb);
  prep_tbl<<<dim3(256), dim3(256), 0, stream>>>(rel_pos_tbl, tbl);

  // Split path needs Q,K,V fragment buffers: 3 * 4096*4*2*1024 shorts.
  const size_t frag_elems = (size_t)4096 * 4 * 2 * 1024;     // per tensor
  const size_t need_bytes = (131072 + 3 * frag_elems) * 2;   // ~201.6 MB
  if (ws_size >= need_bytes) {
    __hip_bfloat16* qg = wsb + 131072;
    __hip_bfloat16* kg = qg + frag_elems;
    __hip_bfloat16* vg = kg + frag_elems;
    qkv_win<<<dim3(4096), dim3(512), 0, stream>>>(x, qkv_bias, wqkvT, qg, kg, vg);
    attn_win<<<dim3(4096), dim3(256), 0, stream>>>(proj_bias, wprojT, tbl,
                                                   qg, kg, vg, out);
  } else {
    swin_attn_fused<<<dim3(4096), dim3(512), 0, stream>>>(x, qkv_bias, proj_bias,
                                                          wqkvT, wprojT, tbl, out);
  }
}

// Round 15
// 136.661 us; speedup vs baseline: 1.5432x; 1.4199x over previous
//
#include <hip/hip_runtime.h>
#include <hip/hip_bf16.h>

#define WIN 7
#define SHIFT_SZ 3
#define WSQ 49
#define CH 128
#define HW 56
#define LOG2E 1.4426950408889634f
#define QSCALE (0.17677669529663687f * LOG2E)

typedef short s16x8 __attribute__((ext_vector_type(8)));
typedef short s16x4 __attribute__((ext_vector_type(4)));
typedef float f32x4 __attribute__((ext_vector_type(4)));

static __device__ __forceinline__ f32x4 mfma16(s16x4 a, s16x4 b, f32x4 c) {
#if __has_builtin(__builtin_amdgcn_mfma_f32_16x16x16bf16_1k)
  return __builtin_amdgcn_mfma_f32_16x16x16bf16_1k(a, b, c, 0, 0, 0);
#else
  f32x4 d;
  asm("v_mfma_f32_16x16x16_bf16 %0, %1, %2, %3" : "=v"(d) : "v"(a), "v"(b), "v"(c));
  return d;
#endif
}

// ---------------- prep kernels (R8 verbatim) ----------------

__global__ void prep_weights(const float* __restrict__ qkv_kernel,
                             const float* __restrict__ proj_kernel,
                             __hip_bfloat16* __restrict__ ws) {
  int idx = blockIdx.x * 256 + threadIdx.x;
  if (idx < 49152) {                      // WqkvT [384][128]
    int n = idx >> 7, c = idx & 127;
    ws[idx] = __float2bfloat16(qkv_kernel[c * 384 + n]);
  }
  if (idx < 16384) {                      // WprojT [128][128]
    int n = idx >> 7, c = idx & 127;
    ws[49152 + idx] = __float2bfloat16(proj_kernel[c * 128 + n]);
  }
}

// Only 4 distinct shift masks exist: cls = (wy==7)*2 + (wx==7).
__global__ void prep_tbl(const float* __restrict__ rel_pos_table,
                         __hip_bfloat16* __restrict__ tbl) {
  int idx = blockIdx.x * 256 + threadIdx.x;   // 65536 total
  int t = idx & 63;
  int s = (idx >> 6) & 63;
  int h = (idx >> 12) & 3;
  int cls = idx >> 14;                        // 0..3
  float v;
  if (t >= WSQ) v = -43280.f;
  else if (s >= WSQ) v = 0.f;
  else {
    int i1 = s / 7, j1 = s % 7, i2 = t / 7, j2 = t % 7;
    int ridx = (i1 - i2 + 6) * 13 + (j1 - j2 + 6);
    float bias = rel_pos_table[ridx * 4 + h];
    int wyIs7 = cls >> 1, wxIs7 = cls & 1;
    int rh1 = wyIs7 ? (i1 < 4 ? 1 : 2) : 0;
    int rh2 = wyIs7 ? (i2 < 4 ? 1 : 2) : 0;
    int rw1 = wxIs7 ? (j1 < 4 ? 1 : 2) : 0;
    int rw2 = wxIs7 ? (j2 < 4 ? 1 : 2) : 0;
    float mask = (rh1 == rh2 && rw1 == rw2) ? 0.f : -100.f;
    v = (bias + mask) * LOG2E;
  }
  tbl[idx] = __float2bfloat16(v);
}

// ---------------- fused main kernel (R8 + P-in-registers PV) ----------------
// one block = one window (4096 blocks), 512 threads = 8 waves.
// LDS 53248 B (3 blocks/CU), time-multiplexed:
//   [0,18432)      a [64][128] swz, then q [4][64][36], then o [64][128] swz
//   [18432,36864)  k [4][64][36]
//   [36864,53248)  vt [4][32][64] 8B-blk XOR-swz
// P NEVER touches LDS: swapped QK^T leaves P with lane=s-row, regs=t --
// exactly the mfma16 B-operand layout (R12-verified); PV reads V as b64
// fragments from vt. Deferred normalization: O scaled by inv[m] post-PV.
// Barriers (5, was 6): b1 x staged | b2 a reads done (q write ok) |
//   b3 q/k/vt visible | b4 q/k reads done (o region free) | b5 o visible.

__launch_bounds__(512, 6)
__global__ void swin_attn(const float* __restrict__ x,
                          const float* __restrict__ qkv_bias,
                          const float* __restrict__ proj_bias,
                          const __hip_bfloat16* __restrict__ wqkvT,
                          const __hip_bfloat16* __restrict__ wprojT,
                          const __hip_bfloat16* __restrict__ tbl,
                          float* __restrict__ out) {
  __shared__ __align__(16) char smem[53248];
  __hip_bfloat16* a_lds  = (__hip_bfloat16*)smem;             // [64][128] swz
  __hip_bfloat16* q_lds  = (__hip_bfloat16*)smem;             // [4][64][36]
  __hip_bfloat16* k_lds  = (__hip_bfloat16*)(smem + 18432);   // [4][64][36]
  __hip_bfloat16* vt_lds = (__hip_bfloat16*)(smem + 36864);   // [4][32][64] swz
  __hip_bfloat16* o_lds  = (__hip_bfloat16*)smem;             // [64][128] swz

  const int tid = threadIdx.x;
  const int lane = tid & 63;
  const int wv = tid >> 6;          // wave 0..7
  const int g = lane >> 4;          // quarter-wave group
  const int c = lane & 15;
  const int e = c & 7;              // 8-short block XOR mask (rows ≡ c mod 8)

  const int widx = blockIdx.x;
  const int b  = widx >> 6;
  const int wy = (widx >> 3) & 7;
  const int wx = widx & 7;
  const int mc = ((wy == 7) ? 2 : 0) + ((wx == 7) ? 1 : 0);

  // ---- phase 1: stage shifted x-window as bf16 (rows 49..63 zero) ----
  for (int it = tid; it < 1024; it += 512) {
    int s = it >> 4;
    int l16 = it & 15;
    union { s16x8 v; __hip_bfloat16 h[8]; } u;
    if (s < WSQ) {
      int i = s / 7, j = s - i * 7;
      int hh = wy * 7 + i + SHIFT_SZ; if (hh >= HW) hh -= HW;
      int ww = wx * 7 + j + SHIFT_SZ; if (ww >= HW) ww -= HW;
      const float4* src = (const float4*)(x + (((b * HW + hh) * HW + ww) * CH + l16 * 8));
      float4 f0 = src[0], f1 = src[1];
      u.h[0] = __float2bfloat16(f0.x); u.h[1] = __float2bfloat16(f0.y);
      u.h[2] = __float2bfloat16(f0.z); u.h[3] = __float2bfloat16(f0.w);
      u.h[4] = __float2bfloat16(f1.x); u.h[5] = __float2bfloat16(f1.y);
      u.h[6] = __float2bfloat16(f1.z); u.h[7] = __float2bfloat16(f1.w);
    } else {
      #pragma unroll
      for (int q = 0; q < 8; ++q) u.h[q] = __float2bfloat16(0.f);
    }
    *(s16x8*)(a_lds + s * 128 + ((l16 ^ (s & 7)) * 8)) = u.v;
  }
  __syncthreads();   // b1

  // ---- phase 2, pass A: V tile (n-tile 16+wv), m-major out ----
  {
    f32x4 acc_v[4];
    #pragma unroll
    for (int mt = 0; mt < 4; ++mt) acc_v[mt] = (f32x4){0.f, 0.f, 0.f, 0.f};
    #pragma unroll
    for (int kt = 0; kt < 4; ++kt) {
      s16x8 bv = *(const s16x8*)(wqkvT + (16 * (16 + wv) + c) * 128 + kt * 32 + g * 8);
      #pragma unroll
      for (int mt = 0; mt < 4; ++mt) {
        s16x8 af = *(const s16x8*)(a_lds + (16 * mt + c) * 128 + ((4 * kt + g) ^ e) * 8);
        acc_v[mt] = __builtin_amdgcn_mfma_f32_16x16x32_bf16(af, bv, acc_v[mt], 0, 0, 0);
      }
    }
    // scatter V^T: rows d, cols t; 8B packed, 16B-block swizzle
    int hv = wv >> 1;
    int d = (wv & 1) * 16 + c;
    float bvb = qkv_bias[256 + wv * 16 + c];
    __hip_bfloat16* vdst = vt_lds + (hv * 32 + d) * 64;
    #pragma unroll
    for (int mt = 0; mt < 4; ++mt) {
      union { s16x4 v; __hip_bfloat16 h[4]; } u;
      #pragma unroll
      for (int r = 0; r < 4; ++r) u.h[r] = __float2bfloat16(acc_v[mt][r] + bvb);
      *(s16x4*)(vdst + ((2 * mt + (g >> 1)) ^ e) * 8 + (g & 1) * 4) = u.v;
    }
  }

  // ---- phase 2, pass B: Q/K tiles {2wv, 2wv+1}, n-major out ----
  {
    f32x4 acc[2][4];
    #pragma unroll
    for (int ntl = 0; ntl < 2; ++ntl)
      #pragma unroll
      for (int mt = 0; mt < 4; ++mt) acc[ntl][mt] = (f32x4){0.f, 0.f, 0.f, 0.f};
    #pragma unroll
    for (int kt = 0; kt < 4; ++kt) {
      s16x8 af[4];
      #pragma unroll
      for (int mt = 0; mt < 4; ++mt)
        af[mt] = *(const s16x8*)(a_lds + (16 * mt + c) * 128 + ((4 * kt + g) ^ e) * 8);
      #pragma unroll
      for (int ntl = 0; ntl < 2; ++ntl) {
        s16x8 bf = *(const s16x8*)(wqkvT + (16 * (2 * wv + ntl) + c) * 128 + kt * 32 + g * 8);
        #pragma unroll
        for (int mt = 0; mt < 4; ++mt)
          acc[ntl][mt] = __builtin_amdgcn_mfma_f32_16x16x32_bf16(bf, af[mt], acc[ntl][mt], 0, 0, 0);
      }
    }
    const float scale = (wv < 4) ? QSCALE : 1.0f;
    // waves 4-7 own K tiles -> region disjoint from a_lds, scatter pre-barrier
    if (wv >= 4) {
      #pragma unroll
      for (int ntl = 0; ntl < 2; ++ntl) {
        int qt = 2 * wv + ntl;
        int h = (qt >> 1) & 3;
        int d0 = (qt & 1) * 16 + 4 * g;
        float4 b4 = *(const float4*)(qkv_bias + qt * 16 + 4 * g);
        __hip_bfloat16* dst = k_lds + h * 2304 + d0;
        #pragma unroll
        for (int mt = 0; mt < 4; ++mt) {
          union { s16x4 v; __hip_bfloat16 h[4]; } u;
          u.h[0] = __float2bfloat16((acc[ntl][mt][0] + b4.x) * scale);
          u.h[1] = __float2bfloat16((acc[ntl][mt][1] + b4.y) * scale);
          u.h[2] = __float2bfloat16((acc[ntl][mt][2] + b4.z) * scale);
          u.h[3] = __float2bfloat16((acc[ntl][mt][3] + b4.w) * scale);
          *(s16x4*)(dst + (16 * mt + c) * 36) = u.v;
        }
      }
    }
    __syncthreads();   // b2: all a_lds reads done
    if (wv < 4) {
      #pragma unroll
      for (int ntl = 0; ntl < 2; ++ntl) {
        int qt = 2 * wv + ntl;
        int h = (qt >> 1) & 3;
        int d0 = (qt & 1) * 16 + 4 * g;
        float4 b4 = *(const float4*)(qkv_bias + qt * 16 + 4 * g);
        __hip_bfloat16* dst = q_lds + h * 2304 + d0;
        #pragma unroll
        for (int mt = 0; mt < 4; ++mt) {
          union { s16x4 v; __hip_bfloat16 h[4]; } u;
          u.h[0] = __float2bfloat16((acc[ntl][mt][0] + b4.x) * scale);
          u.h[1] = __float2bfloat16((acc[ntl][mt][1] + b4.y) * scale);
          u.h[2] = __float2bfloat16((acc[ntl][mt][2] + b4.z) * scale);
          u.h[3] = __float2bfloat16((acc[ntl][mt][3] + b4.w) * scale);
          *(s16x4*)(dst + (16 * mt + c) * 36) = u.v;
        }
      }
    }
  }
  __syncthreads();   // b3: q/k/vt visible

  // ---- phase 3a: preload q/k fragments ----
  const int h3 = wv >> 1;
  const int mh = wv & 1;
  s16x8 qf[2], kf[4];
  #pragma unroll
  for (int m = 0; m < 2; ++m) {
    const __hip_bfloat16* p = q_lds + (h3 * 64 + 16 * (2 * mh + m) + c) * 36 + g * 8;
    *(s16x4*)&qf[m] = *(const s16x4*)p;
    *(((s16x4*)&qf[m]) + 1) = *(const s16x4*)(p + 4);
  }
  #pragma unroll
  for (int nt = 0; nt < 4; ++nt) {
    const __hip_bfloat16* p = k_lds + (h3 * 64 + 16 * nt + c) * 36 + g * 8;
    *(s16x4*)&kf[nt] = *(const s16x4*)p;
    *(((s16x4*)&kf[nt]) + 1) = *(const s16x4*)(p + 4);
  }
  __syncthreads();   // b4: q/k reads done; region @0 free for o

  // ---- preload V fragments (b64, swizzle-consistent with pass-A writer) ----
  // vf16[vt][nt]: A-operand of mfma16, lane c = d-row, regs = token 4g+j
  s16x4 vf16[2][4];
  #pragma unroll
  for (int vt = 0; vt < 2; ++vt)
    #pragma unroll
    for (int nt = 0; nt < 4; ++nt)
      vf16[vt][nt] = *(const s16x4*)(vt_lds + (h3 * 32 + 16 * vt + c) * 64 +
                                     ((2 * nt + (g >> 1)) ^ e) * 8 + (g & 1) * 4);

  // ---- phase 3b: QK^T (t-major) + in-reg softmax + PV with P in regs ----
  #pragma unroll
  for (int m = 0; m < 2; ++m) {
    f32x4 sc[4];
    #pragma unroll
    for (int nt = 0; nt < 4; ++nt) {
      sc[nt] = (f32x4){0.f, 0.f, 0.f, 0.f};
      sc[nt] = __builtin_amdgcn_mfma_f32_16x16x32_bf16(kf[nt], qf[m], sc[nt], 0, 0, 0);
    }
    const __hip_bfloat16* tb_ =
        tbl + (((mc << 2) + h3) << 12) + (32 * mh + 16 * m + c) * 64;
    #pragma unroll
    for (int nt = 0; nt < 4; ++nt) {
      union { s16x4 v; __hip_bfloat16 h[4]; } tv;
      tv.v = *(const s16x4*)(tb_ + 16 * nt + 4 * g);
      #pragma unroll
      for (int r = 0; r < 4; ++r) sc[nt][r] += __bfloat162float(tv.h[r]);
    }
    float mx = -1e30f;
    #pragma unroll
    for (int nt = 0; nt < 4; ++nt)
      #pragma unroll
      for (int r = 0; r < 4; ++r) mx = fmaxf(mx, sc[nt][r]);
    mx = fmaxf(mx, __shfl_xor(mx, 16));
    mx = fmaxf(mx, __shfl_xor(mx, 32));
    float sum = 0.f;
    #pragma unroll
    for (int nt = 0; nt < 4; ++nt)
      #pragma unroll
      for (int r = 0; r < 4; ++r) {
        float ex = __builtin_amdgcn_exp2f(sc[nt][r] - mx);
        sc[nt][r] = ex;
        sum += ex;
      }
    // pack UNNORMALIZED P (lane c = s-row, elem j = t within nt block)
    s16x4 pf[4];
    #pragma unroll
    for (int nt = 0; nt < 4; ++nt) {
      union { s16x4 v; __hip_bfloat16 h[4]; } u;
      #pragma unroll
      for (int r = 0; r < 4; ++r) u.h[r] = __float2bfloat16(sc[nt][r]);
      pf[nt] = u.v;
    }
    sum += __shfl_xor(sum, 16);
    sum += __shfl_xor(sum, 32);
    float inv = __builtin_amdgcn_rcpf(sum);
    // PV: mfma16(V^T frag, P frag) -> lane c = s-row, regs = d quad (R12-verified)
    #pragma unroll
    for (int vt = 0; vt < 2; ++vt) {
      f32x4 oacc = (f32x4){0.f, 0.f, 0.f, 0.f};
      #pragma unroll
      for (int nt = 0; nt < 4; ++nt)
        oacc = mfma16(vf16[vt][nt], pf[nt], oacc);
      union { s16x4 v; __hip_bfloat16 h[4]; } u;
      #pragma unroll
      for (int r = 0; r < 4; ++r) u.h[r] = __float2bfloat16(oacc[r] * inv);
      *(s16x4*)(o_lds + (32 * mh + 16 * m + c) * 128 +
                ((4 * h3 + 2 * vt + (g >> 1)) ^ e) * 8 + (g & 1) * 4) = u.v;
    }
  }
  __syncthreads();   // b5: o visible

  // ---- phase 4: proj GEMM (n-major out -> float4 stores) ----
  {
    f32x4 pacc[4];
    #pragma unroll
    for (int mt = 0; mt < 4; ++mt) pacc[mt] = (f32x4){0.f, 0.f, 0.f, 0.f};
    #pragma unroll
    for (int kt = 0; kt < 4; ++kt) {
      s16x8 bfp = *(const s16x8*)(wprojT + (16 * wv + c) * 128 + kt * 32 + g * 8);
      #pragma unroll
      for (int mt = 0; mt < 4; ++mt) {
        s16x8 afo = *(const s16x8*)(o_lds + (16 * mt + c) * 128 + ((4 * kt + g) ^ e) * 8);
        pacc[mt] = __builtin_amdgcn_mfma_f32_16x16x32_bf16(bfp, afo, pacc[mt], 0, 0, 0);
      }
    }
    float4 pb4 = *(const float4*)(proj_bias + 16 * wv + 4 * g);
    #pragma unroll
    for (int mt = 0; mt < 4; ++mt) {
      int s = 16 * mt + c;
      if (s < WSQ) {
        int i = s / 7, j = s - i * 7;
        int hh = wy * 7 + i + SHIFT_SZ; if (hh >= HW) hh -= HW;
        int ww = wx * 7 + j + SHIFT_SZ; if (ww >= HW) ww -= HW;
        float4 v;
        v.x = pacc[mt][0] + pb4.x;
        v.y = pacc[mt][1] + pb4.y;
        v.z = pacc[mt][2] + pb4.z;
        v.w = pacc[mt][3] + pb4.w;
        *(float4*)(out + ((b * HW + hh) * HW + ww) * CH + 16 * wv + 4 * g) = v;
      }
    }
  }
}

extern "C" void kernel_launch(void* const* d_in, const int* in_sizes, int n_in,
                              void* d_out, int out_size, void* d_ws, size_t ws_size,
                              hipStream_t stream) {
  const float* x            = (const float*)d_in[0];
  const float* qkv_kernel   = (const float*)d_in[1];
  const float* qkv_bias     = (const float*)d_in[2];
  const float* proj_kernel  = (const float*)d_in[3];
  const float* proj_bias    = (const float*)d_in[4];
  const float* rel_pos_tbl  = (const float*)d_in[5];
  float* out = (float*)d_out;

  __hip_bfloat16* wsb    = (__hip_bfloat16*)d_ws;
  __hip_bfloat16* wqkvT  = wsb;            // 49152 elems
  __hip_bfloat16* wprojT = wsb + 49152;    // 16384 elems
  __hip_bfloat16* tbl    = wsb + 65536;    // 65536 elems (4 mask classes)

  prep_weights<<<dim3(192), dim3(256), 0, stream>>>(qkv_kernel, proj_kernel, wsb);
  prep_tbl<<<dim3(256), dim3(256), 0, stream>>>(rel_pos_tbl, tbl);
  swin_attn<<<dim3(4096), dim3(512), 0, stream>>>(x, qkv_bias, proj_bias,
                                                  wqkvT, wprojT, tbl, out);
}

// Round 16
// 127.132 us; speedup vs baseline: 1.6589x; 1.0750x over previous
//
#include <hip/hip_runtime.h>
#include <hip/hip_bf16.h>

#define WIN 7
#define SHIFT_SZ 3
#define WSQ 49
#define CH 128
#define HW 56
#define LOG2E 1.4426950408889634f
#define QSCALE (0.17677669529663687f * LOG2E)

typedef short s16x8 __attribute__((ext_vector_type(8)));
typedef short s16x4 __attribute__((ext_vector_type(4)));
typedef float f32x4 __attribute__((ext_vector_type(4)));

// ---------------- prep kernels ----------------

__global__ void prep_weights(const float* __restrict__ qkv_kernel,
                             const float* __restrict__ proj_kernel,
                             __hip_bfloat16* __restrict__ ws) {
  int idx = blockIdx.x * 256 + threadIdx.x;
  if (idx < 49152) {                      // WqkvT [384][128]
    int n = idx >> 7, c = idx & 127;
    ws[idx] = __float2bfloat16(qkv_kernel[c * 384 + n]);
  }
  if (idx < 16384) {                      // WprojT [128][128]
    int n = idx >> 7, c = idx & 127;
    ws[49152 + idx] = __float2bfloat16(proj_kernel[c * 128 + n]);
  }
}

// Only 4 distinct shift masks exist: cls = (wy==7)*2 + (wx==7).
// tbl[cls][h][s][t] = LOG2E * (rel_pos_bias(s,t) + mask(cls,s,t));
// cols t>=49 -> -43280 (kills padded keys), rows s>=49 (dead queries) -> 0
__global__ void prep_tbl(const float* __restrict__ rel_pos_table,
                         __hip_bfloat16* __restrict__ tbl) {
  int idx = blockIdx.x * 256 + threadIdx.x;   // 65536 total
  int t = idx & 63;
  int s = (idx >> 6) & 63;
  int h = (idx >> 12) & 3;
  int cls = idx >> 14;                        // 0..3
  float v;
  if (t >= WSQ) v = -43280.f;
  else if (s >= WSQ) v = 0.f;
  else {
    int i1 = s / 7, j1 = s % 7, i2 = t / 7, j2 = t % 7;
    int ridx = (i1 - i2 + 6) * 13 + (j1 - j2 + 6);
    float bias = rel_pos_table[ridx * 4 + h];
    int wyIs7 = cls >> 1, wxIs7 = cls & 1;
    int rh1 = wyIs7 ? (i1 < 4 ? 1 : 2) : 0;
    int rh2 = wyIs7 ? (i2 < 4 ? 1 : 2) : 0;
    int rw1 = wxIs7 ? (j1 < 4 ? 1 : 2) : 0;
    int rw2 = wxIs7 ? (j2 < 4 ? 1 : 2) : 0;
    float mask = (rh1 == rh2 && rw1 == rw2) ? 0.f : -100.f;
    v = (bias + mask) * LOG2E;
  }
  tbl[idx] = __float2bfloat16(v);
}

// ---------------- fused main kernel (R8, best measured: 126.8 us) ----------
// one block = one window (4096 blocks), 512 threads = 8 waves.
// LDS 53248 B (3 blocks/CU), time-multiplexed:
//   [0,16384)      a [64][128] XOR-swz          (phase 1-2)
//   [0,18432)      q [4][64][36]                (post-b2 .. b4)
//   [18432,36864)  k [4][64][36]                (pre-b2 .. b4)
//   [36864,53248)  vt [4][32][64] blk-swz       (pass A .. PV)
//   [0,32768)      p [4][64][64] XOR-swz        (post-b4, wave-local)
//   [36864,53248)  o [64][128] XOR-swz          (post-b5 .. proj)
// Balanced point: regs ~85/wave (40 arch + acc) at (512,6); every variant
// adding >=8 live regs spilled (R9/R11/R14); every restructure lost
// (R3/R4/R6/R7/R12/R13). Do not perturb without a new mechanism.

__launch_bounds__(512, 6)
__global__ void swin_attn(const float* __restrict__ x,
                          const float* __restrict__ qkv_bias,
                          const float* __restrict__ proj_bias,
                          const __hip_bfloat16* __restrict__ wqkvT,
                          const __hip_bfloat16* __restrict__ wprojT,
                          const __hip_bfloat16* __restrict__ tbl,
                          float* __restrict__ out) {
  __shared__ __align__(16) char smem[53248];
  __hip_bfloat16* a_lds  = (__hip_bfloat16*)smem;             // [64][128] swz
  __hip_bfloat16* q_lds  = (__hip_bfloat16*)smem;             // [4][64][36]
  __hip_bfloat16* k_lds  = (__hip_bfloat16*)(smem + 18432);   // [4][64][36]
  __hip_bfloat16* vt_lds = (__hip_bfloat16*)(smem + 36864);   // [4][32][64] swz
  __hip_bfloat16* p_lds  = (__hip_bfloat16*)smem;             // [4][64][64] swz
  __hip_bfloat16* o_lds  = (__hip_bfloat16*)(smem + 36864);   // [64][128] swz

  const int tid = threadIdx.x;
  const int lane = tid & 63;
  const int wv = tid >> 6;          // wave 0..7
  const int g = lane >> 4;          // quarter-wave group
  const int c = lane & 15;
  const int e = c & 7;              // XOR mask for rows ≡ c (mod 8)

  const int widx = blockIdx.x;
  const int b  = widx >> 6;
  const int wy = (widx >> 3) & 7;
  const int wx = widx & 7;
  const int mc = ((wy == 7) ? 2 : 0) + ((wx == 7) ? 1 : 0);

  // ---- phase 1: stage shifted x-window as bf16 (rows 49..63 zero) ----
  for (int it = tid; it < 1024; it += 512) {
    int s = it >> 4;
    int l16 = it & 15;
    union { s16x8 v; __hip_bfloat16 h[8]; } u;
    if (s < WSQ) {
      int i = s / 7, j = s - i * 7;
      int hh = wy * 7 + i + SHIFT_SZ; if (hh >= HW) hh -= HW;
      int ww = wx * 7 + j + SHIFT_SZ; if (ww >= HW) ww -= HW;
      const float4* src = (const float4*)(x + (((b * HW + hh) * HW + ww) * CH + l16 * 8));
      float4 f0 = src[0], f1 = src[1];
      u.h[0] = __float2bfloat16(f0.x); u.h[1] = __float2bfloat16(f0.y);
      u.h[2] = __float2bfloat16(f0.z); u.h[3] = __float2bfloat16(f0.w);
      u.h[4] = __float2bfloat16(f1.x); u.h[5] = __float2bfloat16(f1.y);
      u.h[6] = __float2bfloat16(f1.z); u.h[7] = __float2bfloat16(f1.w);
    } else {
      #pragma unroll
      for (int q = 0; q < 8; ++q) u.h[q] = __float2bfloat16(0.f);
    }
    *(s16x8*)(a_lds + s * 128 + ((l16 ^ (s & 7)) * 8)) = u.v;
  }
  __syncthreads();   // b1

  // ---- phase 2, pass A: V tile (n-tile 16+wv), m-major out ----
  {
    f32x4 acc_v[4];
    #pragma unroll
    for (int mt = 0; mt < 4; ++mt) acc_v[mt] = (f32x4){0.f, 0.f, 0.f, 0.f};
    #pragma unroll
    for (int kt = 0; kt < 4; ++kt) {
      s16x8 bv = *(const s16x8*)(wqkvT + (16 * (16 + wv) + c) * 128 + kt * 32 + g * 8);
      #pragma unroll
      for (int mt = 0; mt < 4; ++mt) {
        s16x8 af = *(const s16x8*)(a_lds + (16 * mt + c) * 128 + ((4 * kt + g) ^ e) * 8);
        acc_v[mt] = __builtin_amdgcn_mfma_f32_16x16x32_bf16(af, bv, acc_v[mt], 0, 0, 0);
      }
    }
    // scatter V^T: rows d, cols t; 8B packed, 16B-block swizzle
    int hv = wv >> 1;
    int d = (wv & 1) * 16 + c;
    float bvb = qkv_bias[256 + wv * 16 + c];
    __hip_bfloat16* vdst = vt_lds + (hv * 32 + d) * 64;
    #pragma unroll
    for (int mt = 0; mt < 4; ++mt) {
      union { s16x4 v; __hip_bfloat16 h[4]; } u;
      #pragma unroll
      for (int r = 0; r < 4; ++r) u.h[r] = __float2bfloat16(acc_v[mt][r] + bvb);
      *(s16x4*)(vdst + ((2 * mt + (g >> 1)) ^ e) * 8 + (g & 1) * 4) = u.v;
    }
  }

  // ---- phase 2, pass B: Q/K tiles {2wv, 2wv+1}, n-major out ----
  {
    f32x4 acc[2][4];
    #pragma unroll
    for (int ntl = 0; ntl < 2; ++ntl)
      #pragma unroll
      for (int mt = 0; mt < 4; ++mt) acc[ntl][mt] = (f32x4){0.f, 0.f, 0.f, 0.f};
    #pragma unroll
    for (int kt = 0; kt < 4; ++kt) {
      s16x8 af[4];
      #pragma unroll
      for (int mt = 0; mt < 4; ++mt)
        af[mt] = *(const s16x8*)(a_lds + (16 * mt + c) * 128 + ((4 * kt + g) ^ e) * 8);
      #pragma unroll
      for (int ntl = 0; ntl < 2; ++ntl) {
        s16x8 bf = *(const s16x8*)(wqkvT + (16 * (2 * wv + ntl) + c) * 128 + kt * 32 + g * 8);
        #pragma unroll
        for (int mt = 0; mt < 4; ++mt)
          acc[ntl][mt] = __builtin_amdgcn_mfma_f32_16x16x32_bf16(bf, af[mt], acc[ntl][mt], 0, 0, 0);
      }
    }
    const float scale = (wv < 4) ? QSCALE : 1.0f;
    // waves 4-7 own K tiles -> region disjoint from a_lds, scatter pre-barrier
    if (wv >= 4) {
      #pragma unroll
      for (int ntl = 0; ntl < 2; ++ntl) {
        int qt = 2 * wv + ntl;
        int h = (qt >> 1) & 3;
        int d0 = (qt & 1) * 16 + 4 * g;
        float4 b4 = *(const float4*)(qkv_bias + qt * 16 + 4 * g);
        __hip_bfloat16* dst = k_lds + h * 2304 + d0;
        #pragma unroll
        for (int mt = 0; mt < 4; ++mt) {
          union { s16x4 v; __hip_bfloat16 h[4]; } u;
          u.h[0] = __float2bfloat16((acc[ntl][mt][0] + b4.x) * scale);
          u.h[1] = __float2bfloat16((acc[ntl][mt][1] + b4.y) * scale);
          u.h[2] = __float2bfloat16((acc[ntl][mt][2] + b4.z) * scale);
          u.h[3] = __float2bfloat16((acc[ntl][mt][3] + b4.w) * scale);
          *(s16x4*)(dst + (16 * mt + c) * 36) = u.v;
        }
      }
    }
    __syncthreads();   // b2: all a_lds reads done
    if (wv < 4) {
      #pragma unroll
      for (int ntl = 0; ntl < 2; ++ntl) {
        int qt = 2 * wv + ntl;
        int h = (qt >> 1) & 3;
        int d0 = (qt & 1) * 16 + 4 * g;
        float4 b4 = *(const float4*)(qkv_bias + qt * 16 + 4 * g);
        __hip_bfloat16* dst = q_lds + h * 2304 + d0;
        #pragma unroll
        for (int mt = 0; mt < 4; ++mt) {
          union { s16x4 v; __hip_bfloat16 h[4]; } u;
          u.h[0] = __float2bfloat16((acc[ntl][mt][0] + b4.x) * scale);
          u.h[1] = __float2bfloat16((acc[ntl][mt][1] + b4.y) * scale);
          u.h[2] = __float2bfloat16((acc[ntl][mt][2] + b4.z) * scale);
          u.h[3] = __float2bfloat16((acc[ntl][mt][3] + b4.w) * scale);
          *(s16x4*)(dst + (16 * mt + c) * 36) = u.v;
        }
      }
    }
  }
  __syncthreads();   // b3: q/k/vt visible

  // ---- phase 3a: preload q/k fragments ----
  const int h3 = wv >> 1;
  const int mh = wv & 1;
  s16x8 qf[2], kf[4];
  #pragma unroll
  for (int m = 0; m < 2; ++m) {
    const __hip_bfloat16* p = q_lds + (h3 * 64 + 16 * (2 * mh + m) + c) * 36 + g * 8;
    *(s16x4*)&qf[m] = *(const s16x4*)p;
    *(((s16x4*)&qf[m]) + 1) = *(const s16x4*)(p + 4);
  }
  #pragma unroll
  for (int nt = 0; nt < 4; ++nt) {
    const __hip_bfloat16* p = k_lds + (h3 * 64 + 16 * nt + c) * 36 + g * 8;
    *(s16x4*)&kf[nt] = *(const s16x4*)p;
    *(((s16x4*)&kf[nt]) + 1) = *(const s16x4*)(p + 4);
  }
  __syncthreads();   // b4: q/k reads done; p writes may clobber

  // ---- phase 3b: QK^T (t-major), in-register softmax, swizzled P write ----
  #pragma unroll
  for (int m = 0; m < 2; ++m) {
    f32x4 sc[4];
    #pragma unroll
    for (int nt = 0; nt < 4; ++nt) {
      sc[nt] = (f32x4){0.f, 0.f, 0.f, 0.f};
      sc[nt] = __builtin_amdgcn_mfma_f32_16x16x32_bf16(kf[nt], qf[m], sc[nt], 0, 0, 0);
    }
    const __hip_bfloat16* tb_ =
        tbl + (((mc << 2) + h3) << 12) + (32 * mh + 16 * m + c) * 64;
    #pragma unroll
    for (int nt = 0; nt < 4; ++nt) {
      union { s16x4 v; __hip_bfloat16 h[4]; } tv;
      tv.v = *(const s16x4*)(tb_ + 16 * nt + 4 * g);
      #pragma unroll
      for (int r = 0; r < 4; ++r) sc[nt][r] += __bfloat162float(tv.h[r]);
    }
    float mx = -1e30f;
    #pragma unroll
    for (int nt = 0; nt < 4; ++nt)
      #pragma unroll
      for (int r = 0; r < 4; ++r) mx = fmaxf(mx, sc[nt][r]);
    mx = fmaxf(mx, __shfl_xor(mx, 16));
    mx = fmaxf(mx, __shfl_xor(mx, 32));
    float sum = 0.f;
    #pragma unroll
    for (int nt = 0; nt < 4; ++nt)
      #pragma unroll
      for (int r = 0; r < 4; ++r) {
        float e2 = __builtin_amdgcn_exp2f(sc[nt][r] - mx);
        sc[nt][r] = e2;
        sum += e2;
      }
    sum += __shfl_xor(sum, 16);
    sum += __shfl_xor(sum, 32);
    float inv = __builtin_amdgcn_rcpf(sum);
    __hip_bfloat16* prow = p_lds + (h3 * 64 + 16 * (2 * mh + m) + c) * 64;
    #pragma unroll
    for (int nt = 0; nt < 4; ++nt) {
      union { s16x4 v; __hip_bfloat16 h[4]; } u;
      #pragma unroll
      for (int r = 0; r < 4; ++r) u.h[r] = __float2bfloat16(sc[nt][r] * inv);
      *(s16x4*)(prow + ((2 * nt + (g >> 1)) ^ e) * 8 + (g & 1) * 4) = u.v;
    }
  }

  // ---- PV: O = P @ V, swapped operands -> d-major out ----
  f32x4 oacc[2][2];
  #pragma unroll
  for (int m = 0; m < 2; ++m)
    #pragma unroll
    for (int ntd = 0; ntd < 2; ++ntd) oacc[m][ntd] = (f32x4){0.f, 0.f, 0.f, 0.f};
  #pragma unroll
  for (int kt = 0; kt < 2; ++kt) {
    s16x8 vfr[2], pfr[2];
    #pragma unroll
    for (int ntd = 0; ntd < 2; ++ntd)
      vfr[ntd] = *(const s16x8*)(vt_lds + (h3 * 32 + 16 * ntd + c) * 64 +
                                 (((4 * kt + g) ^ e) * 8));
    #pragma unroll
    for (int m = 0; m < 2; ++m)
      pfr[m] = *(const s16x8*)(p_lds + (h3 * 64 + 16 * (2 * mh + m) + c) * 64 +
                               (((4 * kt + g) ^ e) * 8));
    #pragma unroll
    for (int m = 0; m < 2; ++m)
      #pragma unroll
      for (int ntd = 0; ntd < 2; ++ntd)
        oacc[m][ntd] = __builtin_amdgcn_mfma_f32_16x16x32_bf16(vfr[ntd], pfr[m], oacc[m][ntd], 0, 0, 0);
  }
  __syncthreads();   // b5: p/vt reads done; o writes may clobber vt

  #pragma unroll
  for (int m = 0; m < 2; ++m)
    #pragma unroll
    for (int ntd = 0; ntd < 2; ++ntd) {
      union { s16x4 v; __hip_bfloat16 h[4]; } u;
      #pragma unroll
      for (int r = 0; r < 4; ++r) u.h[r] = __float2bfloat16(oacc[m][ntd][r]);
      *(s16x4*)(o_lds + (32 * mh + 16 * m + c) * 128 +
                ((4 * h3 + 2 * ntd + (g >> 1)) ^ e) * 8 + (g & 1) * 4) = u.v;
    }
  __syncthreads();   // b6: o visible

  // ---- phase 4: proj GEMM (n-major out -> float4 stores) ----
  {
    f32x4 pacc[4];
    #pragma unroll
    for (int mt = 0; mt < 4; ++mt) pacc[mt] = (f32x4){0.f, 0.f, 0.f, 0.f};
    #pragma unroll
    for (int kt = 0; kt < 4; ++kt) {
      s16x8 bfp = *(const s16x8*)(wprojT + (16 * wv + c) * 128 + kt * 32 + g * 8);
      #pragma unroll
      for (int mt = 0; mt < 4; ++mt) {
        s16x8 afo = *(const s16x8*)(o_lds + (16 * mt + c) * 128 + ((4 * kt + g) ^ e) * 8);
        pacc[mt] = __builtin_amdgcn_mfma_f32_16x16x32_bf16(bfp, afo, pacc[mt], 0, 0, 0);
      }
    }
    float4 pb4 = *(const float4*)(proj_bias + 16 * wv + 4 * g);
    #pragma unroll
    for (int mt = 0; mt < 4; ++mt) {
      int s = 16 * mt + c;
      if (s < WSQ) {
        int i = s / 7, j = s - i * 7;
        int hh = wy * 7 + i + SHIFT_SZ; if (hh >= HW) hh -= HW;
        int ww = wx * 7 + j + SHIFT_SZ; if (ww >= HW) ww -= HW;
        float4 v;
        v.x = pacc[mt][0] + pb4.x;
        v.y = pacc[mt][1] + pb4.y;
        v.z = pacc[mt][2] + pb4.z;
        v.w = pacc[mt][3] + pb4.w;
        *(float4*)(out + ((b * HW + hh) * HW + ww) * CH + 16 * wv + 4 * g) = v;
      }
    }
  }
}

extern "C" void kernel_launch(void* const* d_in, const int* in_sizes, int n_in,
                              void* d_out, int out_size, void* d_ws, size_t ws_size,
                              hipStream_t stream) {
  const float* x            = (const float*)d_in[0];
  const float* qkv_kernel   = (const float*)d_in[1];
  const float* qkv_bias     = (const float*)d_in[2];
  const float* proj_kernel  = (const float*)d_in[3];
  const float* proj_bias    = (const float*)d_in[4];
  const float* rel_pos_tbl  = (const float*)d_in[5];
  float* out = (float*)d_out;

  __hip_bfloat16* wsb    = (__hip_bfloat16*)d_ws;
  __hip_bfloat16* wqkvT  = wsb;            // 49152 elems
  __hip_bfloat16* wprojT = wsb + 49152;    // 16384 elems
  __hip_bfloat16* tbl    = wsb + 65536;    // 65536 elems (4 mask classes)

  prep_weights<<<dim3(192), dim3(256), 0, stream>>>(qkv_kernel, proj_kernel, wsb);
  prep_tbl<<<dim3(256), dim3(256), 0, stream>>>(rel_pos_tbl, tbl);
  swin_attn<<<dim3(4096), dim3(512), 0, stream>>>(x, qkv_bias, proj_bias,
                                                  wqkvT, wprojT, tbl, out);
}